// Round 1
// baseline (667.684 us; speedup 1.0000x reference)
//
#include <hip/hip_runtime.h>
#include <hip/hip_bf16.h>
#include <stdint.h>

typedef __attribute__((__ext_vector_type__(8))) __bf16 bf16x8;
typedef __attribute__((__ext_vector_type__(2))) __bf16 bf16x2;
typedef __attribute__((__ext_vector_type__(4))) float  f32x4;
typedef __attribute__((__ext_vector_type__(8))) int    v8i;

// Fixed MX scales (e8m0): A quantized x2^8 -> scale byte 119 (2^-8),
// B quantized x2^6 -> scale byte 121 (2^-6). Byte replicated so any
// op_sel byte selection reads the same value.
#define SCALE_A_DW 0x77777777
#define SCALE_B_DW 0x79797979

// async 16B global->LDS (dest = wave-uniform base + lane*16)
__device__ __forceinline__ void gl_lds16(const void* g, void* l) {
  __builtin_amdgcn_global_load_lds(
      (__attribute__((address_space(1))) void*)(uintptr_t)g,
      (__attribute__((address_space(3))) void*)(unsigned)(uintptr_t)l,
      16, 0, 0);
}

// ---- fused prep: stats / labels / pack_avg / pack_wsp / Aav-zero-row -------
__global__ __launch_bounds__(256) void k_prep(
    const float* __restrict__ x, float* __restrict__ stats,
    const float* __restrict__ seg, int* __restrict__ labels,
    const float* __restrict__ cgw, const float* __restrict__ cbw,
    float* __restrict__ wpa,
    const float* __restrict__ ssw, __bf16* __restrict__ wspb,
    __bf16* __restrict__ Aav) {
  __shared__ __align__(16) char smem[16*401*4];
  int blk = blockIdx.x;
  if (blk < 2048) {                       // ---- instance-norm stats
    int bc = blk;
    const float4* p = (const float4*)(x + (size_t)bc * 4096);
    float s = 0.f, ss = 0.f;
    for (int i = threadIdx.x; i < 1024; i += 256) {
      float4 v = p[i];
      s  += v.x + v.y + v.z + v.w;
      ss += v.x*v.x + v.y*v.y + v.z*v.z + v.w*v.w;
    }
    #pragma unroll
    for (int o = 32; o > 0; o >>= 1) { s += __shfl_down(s, o); ss += __shfl_down(ss, o); }
    float* sh = (float*)smem;
    int wv = threadIdx.x >> 6;
    if ((threadIdx.x & 63) == 0) { sh[wv] = s; sh[4 + wv] = ss; }
    __syncthreads();
    if (threadIdx.x == 0) {
      float S = sh[0]+sh[1]+sh[2]+sh[3], SS = sh[4]+sh[5]+sh[6]+sh[7];
      float m = S * (1.f/4096.f);
      float var = SS * (1.f/4096.f) - m*m;
      stats[bc] = m;
      stats[2048 + bc] = rsqrtf(var + 1e-5f);
    }
  } else if (blk < 2176) {                // ---- labels (last one-hot j)
    int idx = (blk - 2048)*256 + threadIdx.x;       // 0..32767
    int b = idx >> 12, pix = idx & 4095;
    const float* p = seg + (size_t)b*19*4096 + pix;
    int lab = -1;
    for (int j = 0; j < 19; ++j) if (p[(size_t)j*4096] > 0.f) lab = j;
    labels[idx] = lab;
  } else if (blk < 3200) {                // ---- pack avg weights wpa[k5][c][n]
    int bid = blk - 2176;
    float* s = (float*)smem;
    int n0 = (bid & 31) * 16, c0 = (bid >> 5) * 16;
    for (int i = threadIdx.x; i < 6400; i += 256) {
      int nn = i / 400, qq = i % 400;
      int n = n0 + nn;
      const float* src = (n < 256) ? cgw + (size_t)n*12800 : cbw + (size_t)(n-256)*12800;
      s[nn*401 + qq] = src[c0*25 + qq];
    }
    __syncthreads();
    for (int i = threadIdx.x; i < 6400; i += 256) {
      int nn = i & 15, rest = i >> 4;
      int k5 = rest % 25, cc = rest / 25;
      wpa[((size_t)k5*512 + c0 + cc)*512 + n0 + nn] = s[nn*401 + cc*25 + k5];
    }
  } else if (blk < 4200) {                // ---- pack shared weights (j=19 zero)
    int idx = (blk - 3200)*256 + threadIdx.x;       // < 256000
    int o = idx & 511, k5 = (idx >> 9) % 25, j = idx / 12800;
    wspb[idx] = (j < 19) ? (__bf16)ssw[((size_t)o*19 + j)*25 + k5] : (__bf16)0.f;
  } else {                                // ---- Aav zero row 3800
    ((unsigned*)(Aav + 3800ull*512))[threadIdx.x] = 0;   // 256 dwords = 1024 B
  }
}

// ---------------- mu[b,j,e] = relu(sum_d sc[b,j,d]*fc_w[j,e,d] + fc_b) ------
__global__ __launch_bounds__(512) void k_mu(const float* __restrict__ sc,
                                            const float* __restrict__ fcw,
                                            const float* __restrict__ fcb,
                                            float* __restrict__ mu) {
  int b = blockIdx.x / 19, j = blockIdx.x % 19;
  __shared__ float s[512];
  s[threadIdx.x] = sc[(b*19 + j)*512 + threadIdx.x];
  __syncthreads();
  int e = threadIdx.x;
  const float4* w4 = (const float4*)(fcw + ((size_t)(j*512 + e))*512);
  const float4* s4 = (const float4*)s;
  float acc = 0.f;
  for (int d = 0; d < 128; ++d) {
    float4 w = w4[d], v = s4[d];
    acc += w.x*v.x + w.y*v.y + w.z*v.z + w.w*v.w;
  }
  acc += fcb[j*512 + e];
  mu[(b*19 + j)*512 + e] = fmaxf(acc, 0.f);
}

// ---- pack spade weights -> fp8 e4m3, fixed scale x2^6: wq[k5][n][c] --------
__global__ __launch_bounds__(256) void k_pack_spade(
    const float* __restrict__ g, const float* __restrict__ bt,
    uint8_t* __restrict__ wq) {
  int n = blockIdx.x;                               // 0..511
  const float* src = (n < 256) ? g + (size_t)n*12800 : bt + (size_t)(n-256)*12800;
  __shared__ float s[12800];
  for (int i = threadIdx.x; i < 12800; i += 256) s[i] = src[i];
  __syncthreads();
  int t = threadIdx.x;
  for (int k5 = 0; k5 < 25; ++k5) {
    float w0 = s[(2*t)*25 + k5] * 64.f, w1 = s[(2*t+1)*25 + k5] * 64.f;
    int pk = __builtin_amdgcn_cvt_pk_fp8_f32(w0, w1, 0, false);
    *(unsigned short*)(wq + ((size_t)k5*512 + n)*512 + 2*t) = (unsigned short)pk;
  }
}

// ---- A[b,j,k5,n] = sum_c mu[b,j,c]*wpa[k5][c][n]  (mu via scalar loads) ----
__global__ __launch_bounds__(512) void k_A_avg(const float* __restrict__ mu,
                                               const float* __restrict__ wpa,
                                               __bf16* __restrict__ A) {
  int b = blockIdx.x / 25, k5 = blockIdx.x % 25;
  int n = threadIdx.x;
  const float* wp = wpa + (size_t)k5*262144 + n;
  const float* mub = mu + b*19*512;                 // wave-uniform rows -> s_load
  float acc[19];
  #pragma unroll
  for (int j = 0; j < 19; ++j) acc[j] = 0.f;
  for (int c = 0; c < 512; ++c) {
    float w = wp[(size_t)c*512];
    #pragma unroll
    for (int j = 0; j < 19; ++j) acc[j] += mub[j*512 + c] * w;
  }
  #pragma unroll
  for (int j = 0; j < 19; ++j)
    A[((size_t)((b*19 + j)*25 + k5))*512 + n] = (__bf16)acc[j];
}

// ---- actv: debranched gather -> fp8 e4m3 (x2^8) NHWC padded ----------------
// Writes its own zero borders (rows hp<2, hp>=66 and cols wp in {0,1,66,67}).
__global__ void k_actv(const int* __restrict__ labels, const __bf16* __restrict__ wsp,
                       const float* __restrict__ ssb, uint8_t* __restrict__ actv) {
  int b = blockIdx.x / 68, hp = blockIdx.x % 68;
  int t = threadIdx.x;
  size_t rowbase = ((size_t)b*68 + hp)*68;          // padded pixel index base
  if (hp < 2 || hp >= 66) {                         // full zero row
    unsigned* dp = (unsigned*)(actv + rowbase*512);
    for (int i = t; i < 8704; i += 256) dp[i] = 0;
    return;
  }
  int h = hp - 2;
  __shared__ int lab[5*68];
  for (int i = t; i < 5*68; i += 256) {
    int dh = i / 68, xx = i % 68;
    int hh = h + dh - 2, ww = xx - 2;
    int l = 19;
    if (hh >= 0 && hh < 64 && ww >= 0 && ww < 64) {
      int l0 = labels[b*4096 + hh*64 + ww];
      if (l0 >= 0) l = l0;
    }
    lab[i] = l;
  }
  {                                                 // left/right border pixels
    unsigned* dp = (unsigned*)(actv + rowbase*512);
    dp[t] = 0; dp[66*128 + t] = 0;                  // pixels 0,1 and 66,67
  }
  __syncthreads();
  float bs0 = ssb[2*t], bs1 = ssb[2*t + 1];
  for (int w = 0; w < 64; ++w) {
    float a0 = bs0, a1 = bs1;
    #pragma unroll
    for (int tap = 0; tap < 25; ++tap) {
      int l = lab[(tap/5)*68 + w + (tap%5)];        // wave-uniform
      bf16x2 v = *(const bf16x2*)(wsp + (size_t)(l*25 + tap)*512 + 2*t);
      a0 += (float)v[0]; a1 += (float)v[1];
    }
    a0 = fmaxf(a0, 0.f) * 256.f;
    a1 = fmaxf(a1, 0.f) * 256.f;
    int pk = __builtin_amdgcn_cvt_pk_fp8_f32(a0, a1, 0, false);
    *(unsigned short*)(actv + (rowbase + 2 + w)*512 + 2*t) = (unsigned short)pk;
  }
}

// ---- implicit-GEMM conv, MXFP8 fixed-scale: M=32768, N=512, K=12800 --------
// Double-buffered single-barrier pipeline (T3 minimum recipe): issue next
// chunk's global_load_lds BEFORE computing current chunk; the vmcnt(0)
// emitted by the end-of-iteration __syncthreads then waits on loads whose
// latency was hidden under 16 MFMAs. Buffer indices are compile-time
// (manual 2x unroll) so the two LDS halves are provably disjoint.
__global__ __launch_bounds__(256) void k_conv(
    const uint8_t* __restrict__ actv, const uint8_t* __restrict__ wq,
    const float* __restrict__ sgb, const float* __restrict__ sbb,
    __bf16* __restrict__ gbs) {
  __shared__ __align__(16) uint8_t ldsA[2][16384];  // 128 rows x 128 B each
  __shared__ __align__(16) uint8_t ldsB[2][16384];
  const int tid = threadIdx.x, wv = tid >> 6, lane = tid & 63;
  const int l15 = lane & 15, q = lane >> 4;
  const int m0 = blockIdx.x * 128, n0 = blockIdx.y * 128;
  const int b = m0 >> 12;

  int aoff[4], boff[4];                             // staging offsets (bytes)
  #pragma unroll
  for (int i = 0; i < 4; ++i) {
    int p = (wv*4 + i)*64 + lane;                   // 16B slot
    int r = p >> 3, pc = p & 7;
    int cl = pc ^ (r & 7);                          // logical chunk fetched
    int pix = (m0 + r) & 4095;
    int h = pix >> 6, w = pix & 63;
    aoff[i] = ((b*68 + h)*68 + w)*512 + cl*16;
    boff[i] = (n0 + r)*512 + cl*16;
  }

  const int wm = (wv >> 1) * 64, wn = (wv & 1) * 64;
  f32x4 acc[4][4] = {};

  // stage K-chunk t (t = k5*4 + kc) into LDS buffer `buf`
  auto stage = [&](int t, int buf) {
    int k5 = t >> 2, kc = t & 3;
    int a_k = ((k5/5)*68 + (k5%5))*512 + kc*128;
    int b_k = k5*262144 + kc*128;
    uint8_t* la = &ldsA[buf][0];
    uint8_t* lb = &ldsB[buf][0];
    #pragma unroll
    for (int i = 0; i < 4; ++i) {
      gl_lds16(actv + aoff[i] + a_k, la + (wv*4 + i)*1024);
      gl_lds16(wq   + boff[i] + b_k, lb + (wv*4 + i)*1024);
    }
  };

  // compute K-chunk from LDS buffer `buf` (call with literal 0/1)
  auto compute = [&](int buf) {
    v8i bfr[4];
    #pragma unroll
    for (int ni = 0; ni < 4; ++ni) {
      int row = wn + ni*16 + l15;
      const uint8_t* base = &ldsB[buf][row*128];
      union { v8i v; uint4 u[2]; } tt;
      tt.u[0] = *(const uint4*)(base + ((2*q    ) ^ (row & 7))*16);
      tt.u[1] = *(const uint4*)(base + ((2*q + 1) ^ (row & 7))*16);
      bfr[ni] = tt.v;
    }
    #pragma unroll
    for (int mi = 0; mi < 4; ++mi) {
      int row = wm + mi*16 + l15;
      const uint8_t* base = &ldsA[buf][row*128];
      union { v8i v; uint4 u[2]; } tt;
      tt.u[0] = *(const uint4*)(base + ((2*q    ) ^ (row & 7))*16);
      tt.u[1] = *(const uint4*)(base + ((2*q + 1) ^ (row & 7))*16);
      v8i af = tt.v;
      #pragma unroll
      for (int ni = 0; ni < 4; ++ni)
        acc[mi][ni] = __builtin_amdgcn_mfma_scale_f32_16x16x128_f8f6f4(
            af, bfr[ni], acc[mi][ni], 0, 0, 0, SCALE_A_DW, 0, SCALE_B_DW);
    }
  };

  stage(0, 0);
  __syncthreads();                                  // only exposed-latency wait
  for (int tt = 0; tt < 50; ++tt) {
    int t = 2*tt;
    stage(t + 1, 1);                                // prefetch next (always valid: t+1<=99)
    compute(0);
    __syncthreads();                                // drains vmcnt: buf1 ready
    if (tt < 49) stage(t + 2, 0);                   // prefetch next-next
    compute(1);
    __syncthreads();                                // drains vmcnt: buf0 ready
  }

  // epilogue: D[row=q*4+r][col=l15]; NHWC store gbs[m][n] (+spade bias)
  #pragma unroll
  for (int ni = 0; ni < 4; ++ni) {
    int n = n0 + wn + ni*16 + l15;
    float bias = (n < 256) ? sgb[n] : sbb[n - 256];
    #pragma unroll
    for (int mi = 0; mi < 4; ++mi) {
      int m = m0 + wm + mi*16 + q*4;
      size_t base = (size_t)m*512 + n;
      #pragma unroll
      for (int r = 0; r < 4; ++r)
        gbs[base + (size_t)r*512] = (__bf16)(acc[mi][ni][r] + bias);
    }
  }
}

// ---- avg path: debranched 25-tap gather, 16 px/block, NHWC out -------------
__global__ void k_gather(const int* __restrict__ labels, const __bf16* __restrict__ A,
                         const float* __restrict__ cgb, const float* __restrict__ cbb,
                         __bf16* __restrict__ gba) {
  int wt = blockIdx.x & 3, h = (blockIdx.x >> 2) & 63, b = blockIdx.x >> 8;
  int w0 = wt * 16;
  __shared__ int rowbase[5*20];
  for (int i = threadIdx.x; i < 100; i += 256) {
    int dh = i / 20, xx = i % 20;
    int hh = h + dh - 2, ww = w0 + xx - 2;
    int l = (hh >= 0 && hh < 64 && ww >= 0 && ww < 64) ? labels[b*4096 + hh*64 + ww] : -1;
    rowbase[i] = (l >= 0) ? (b*19 + l)*25 : -1;
  }
  __syncthreads();
  int t = threadIdx.x;
  float bs0, bs1;
  if (2*t < 256) { bs0 = cgb[2*t]; bs1 = cgb[2*t + 1]; }
  else           { bs0 = cbb[2*t - 256]; bs1 = cbb[2*t - 255]; }
  for (int px = 0; px < 16; ++px) {
    float a0 = bs0, a1 = bs1;
    #pragma unroll
    for (int tap = 0; tap < 25; ++tap) {
      int rb = rowbase[(tap/5)*20 + px + (tap%5)];
      int row = (rb >= 0) ? rb + tap : 3800;
      bf16x2 v = *(const bf16x2*)(A + (size_t)row*512 + 2*t);
      a0 += (float)v[0]; a1 += (float)v[1];
    }
    size_t o = ((size_t)b*4096 + h*64 + w0 + px) * 512;
    bf16x2 r; r[0] = (__bf16)a0; r[1] = (__bf16)a1;
    *(bf16x2*)(gba + o + 2*t) = r;
  }
}

// ---- final blend: NHWC->NCHW via LDS transpose -----------------------------
__global__ __launch_bounds__(256) void k_final(
    const float* __restrict__ x, const float* __restrict__ stats,
    const __bf16* __restrict__ gba, const __bf16* __restrict__ gbs,
    const float* __restrict__ blg, const float* __restrict__ blb,
    float* __restrict__ out) {
  __shared__ __bf16 tg_av[64*66], tb_av[64*66], tg_sp[64*66], tb_sp[64*66];
  int bidx = blockIdx.x;                   // 8b x 4ct x 64pt
  int pt = bidx & 63, ct = (bidx >> 6) & 3, b = bidx >> 8;
  int c0 = ct*64, p0 = pt*64;
  for (int i = threadIdx.x; i < 4096; i += 256) {
    int p = i >> 6, c = i & 63;
    size_t src = ((size_t)b*4096 + p0 + p)*512;
    int d = p*66 + c;
    tg_av[d] = gba[src + c0 + c];
    tb_av[d] = gba[src + 256 + c0 + c];
    tg_sp[d] = gbs[src + c0 + c];
    tb_sp[d] = gbs[src + 256 + c0 + c];
  }
  __syncthreads();
  float ga = 1.f / (1.f + expf(-blg[0]));
  float ba = 1.f / (1.f + expf(-blb[0]));
  int p = threadIdx.x & 63;
  for (int cl = threadIdx.x >> 6; cl < 64; cl += 4) {
    int c = c0 + cl;
    int bc = b*256 + c;
    float mean = stats[bc], rstd = stats[2048 + bc];
    size_t o = (size_t)bc*4096 + p0 + p;
    int d = p*66 + cl;
    float gf  = ga*(float)tg_av[d] + (1.f - ga)*(float)tg_sp[d];
    float bf_ = ba*(float)tb_av[d] + (1.f - ba)*(float)tb_sp[d];
    out[o] = (x[o] - mean)*rstd*(1.f + gf) + bf_;
  }
}

extern "C" void kernel_launch(void* const* d_in, const int* in_sizes, int n_in,
                              void* d_out, int out_size, void* d_ws, size_t ws_size,
                              hipStream_t stream) {
  const float* x    = (const float*)d_in[0];
  const float* seg  = (const float*)d_in[1];
  const float* sc   = (const float*)d_in[2];
  const float* fcw  = (const float*)d_in[3];
  const float* fcb  = (const float*)d_in[4];
  const float* cgw  = (const float*)d_in[5];
  const float* cgb  = (const float*)d_in[6];
  const float* cbw  = (const float*)d_in[7];
  const float* cbb  = (const float*)d_in[8];
  const float* ssw  = (const float*)d_in[9];
  const float* ssb  = (const float*)d_in[10];
  const float* sgw  = (const float*)d_in[11];
  const float* sgb  = (const float*)d_in[12];
  const float* sbw  = (const float*)d_in[13];
  const float* sbb  = (const float*)d_in[14];
  const float* blg  = (const float*)d_in[15];
  const float* blb  = (const float*)d_in[16];
  float* out = (float*)d_out;

  char* ws = (char*)d_ws;
  size_t off = 0;
  auto alloc = [&](size_t bytes) {
    void* p = ws + off; off += (bytes + 255) & ~(size_t)255; return p;
  };
  float*   stats = (float*)alloc(2048ull*2*4);
  int*     labels= (int*)  alloc(32768ull*4);
  float*   mu    = (float*)alloc(77824ull*4);
  __bf16*  Aav   = (__bf16*)alloc((3800ull + 1)*512*2);  // + zero row 3800
  __bf16*  wspb  = (__bf16*)alloc(20ull*25*512*2);       // j=19 zero rows
  float*   wpa   = (float*)alloc(25ull*512*512*4);       // 26.2 MB
  uint8_t* wq    = (uint8_t*)alloc(25ull*512*512);       // 6.6 MB fp8
  uint8_t* actv  = (uint8_t*)alloc(8ull*68*68*512);      // 18.9 MB fp8 NHWC pad
  __bf16*  gba   = (__bf16*)alloc(8ull*4096*512*2);      // 33.5 MB (NHWC)
  __bf16*  gbs   = (__bf16*)alloc(8ull*4096*512*2);      // 33.5 MB (NHWC)

  k_prep      <<<4201, 256, 0, stream>>>(x, stats, seg, labels, cgw, cbw, wpa, ssw, wspb, Aav);
  k_mu        <<<152, 512, 0, stream>>>(sc, fcw, fcb, mu);
  k_pack_spade<<<512, 256, 0, stream>>>(sgw, sbw, wq);
  k_A_avg     <<<200, 512, 0, stream>>>(mu, wpa, Aav);
  k_actv      <<<544, 256, 0, stream>>>(labels, wspb, ssb, actv);
  k_conv      <<<dim3(256, 4), 256, 0, stream>>>(actv, wq, sgb, sbb, gbs);
  k_gather    <<<2048, 256, 0, stream>>>(labels, Aav, cgb, cbb, gba);
  k_final     <<<2048, 256, 0, stream>>>(x, stats, gba, gbs, blg, blb, out);
}

// Round 2
// 641.444 us; speedup vs baseline: 1.0409x; 1.0409x over previous
//
#include <hip/hip_runtime.h>
#include <hip/hip_bf16.h>
#include <stdint.h>

typedef __attribute__((__ext_vector_type__(8))) __bf16 bf16x8;
typedef __attribute__((__ext_vector_type__(2))) __bf16 bf16x2;
typedef __attribute__((__ext_vector_type__(4))) float  f32x4;
typedef __attribute__((__ext_vector_type__(8))) int    v8i;

// Fixed MX scales (e8m0): A quantized x2^8 -> scale byte 119 (2^-8),
// B quantized x2^6 -> scale byte 121 (2^-6). Byte replicated so any
// op_sel byte selection reads the same value.
#define SCALE_A_DW 0x77777777
#define SCALE_B_DW 0x79797979

// async 16B global->LDS (dest = wave-uniform base + lane*16)
__device__ __forceinline__ void gl_lds16(const void* g, void* l) {
  __builtin_amdgcn_global_load_lds(
      (__attribute__((address_space(1))) void*)(uintptr_t)g,
      (__attribute__((address_space(3))) void*)(unsigned)(uintptr_t)l,
      16, 0, 0);
}

// ---- fused prep: stats / labels / pack_avg / pack_wsp / Aav-zero-row -------
__global__ __launch_bounds__(256) void k_prep(
    const float* __restrict__ x, float* __restrict__ stats,
    const float* __restrict__ seg, int* __restrict__ labels,
    const float* __restrict__ cgw, const float* __restrict__ cbw,
    float* __restrict__ wpa,
    const float* __restrict__ ssw, __bf16* __restrict__ wspb,
    __bf16* __restrict__ Aav) {
  __shared__ __align__(16) char smem[16*401*4];
  int blk = blockIdx.x;
  if (blk < 2048) {                       // ---- instance-norm stats
    int bc = blk;
    const float4* p = (const float4*)(x + (size_t)bc * 4096);
    float s = 0.f, ss = 0.f;
    for (int i = threadIdx.x; i < 1024; i += 256) {
      float4 v = p[i];
      s  += v.x + v.y + v.z + v.w;
      ss += v.x*v.x + v.y*v.y + v.z*v.z + v.w*v.w;
    }
    #pragma unroll
    for (int o = 32; o > 0; o >>= 1) { s += __shfl_down(s, o); ss += __shfl_down(ss, o); }
    float* sh = (float*)smem;
    int wv = threadIdx.x >> 6;
    if ((threadIdx.x & 63) == 0) { sh[wv] = s; sh[4 + wv] = ss; }
    __syncthreads();
    if (threadIdx.x == 0) {
      float S = sh[0]+sh[1]+sh[2]+sh[3], SS = sh[4]+sh[5]+sh[6]+sh[7];
      float m = S * (1.f/4096.f);
      float var = SS * (1.f/4096.f) - m*m;
      stats[bc] = m;
      stats[2048 + bc] = rsqrtf(var + 1e-5f);
    }
  } else if (blk < 2176) {                // ---- labels (last one-hot j)
    int idx = (blk - 2048)*256 + threadIdx.x;       // 0..32767
    int b = idx >> 12, pix = idx & 4095;
    const float* p = seg + (size_t)b*19*4096 + pix;
    int lab = -1;
    for (int j = 0; j < 19; ++j) if (p[(size_t)j*4096] > 0.f) lab = j;
    labels[idx] = lab;
  } else if (blk < 3200) {                // ---- pack avg weights wpa[k5][c][n]
    int bid = blk - 2176;
    float* s = (float*)smem;
    int n0 = (bid & 31) * 16, c0 = (bid >> 5) * 16;
    for (int i = threadIdx.x; i < 6400; i += 256) {
      int nn = i / 400, qq = i % 400;
      int n = n0 + nn;
      const float* src = (n < 256) ? cgw + (size_t)n*12800 : cbw + (size_t)(n-256)*12800;
      s[nn*401 + qq] = src[c0*25 + qq];
    }
    __syncthreads();
    for (int i = threadIdx.x; i < 6400; i += 256) {
      int nn = i & 15, rest = i >> 4;
      int k5 = rest % 25, cc = rest / 25;
      wpa[((size_t)k5*512 + c0 + cc)*512 + n0 + nn] = s[nn*401 + cc*25 + k5];
    }
  } else if (blk < 4200) {                // ---- pack shared weights (j=19 zero)
    int idx = (blk - 3200)*256 + threadIdx.x;       // < 256000
    int o = idx & 511, k5 = (idx >> 9) % 25, j = idx / 12800;
    wspb[idx] = (j < 19) ? (__bf16)ssw[((size_t)o*19 + j)*25 + k5] : (__bf16)0.f;
  } else {                                // ---- Aav zero row 3800
    ((unsigned*)(Aav + 3800ull*512))[threadIdx.x] = 0;   // 256 dwords = 1024 B
  }
}

// ---------------- mu[b,j,e] = relu(sum_d sc[b,j,d]*fc_w[j,e,d] + fc_b) ------
__global__ __launch_bounds__(512) void k_mu(const float* __restrict__ sc,
                                            const float* __restrict__ fcw,
                                            const float* __restrict__ fcb,
                                            float* __restrict__ mu) {
  int b = blockIdx.x / 19, j = blockIdx.x % 19;
  __shared__ float s[512];
  s[threadIdx.x] = sc[(b*19 + j)*512 + threadIdx.x];
  __syncthreads();
  int e = threadIdx.x;
  const float4* w4 = (const float4*)(fcw + ((size_t)(j*512 + e))*512);
  const float4* s4 = (const float4*)s;
  float acc = 0.f;
  for (int d = 0; d < 128; ++d) {
    float4 w = w4[d], v = s4[d];
    acc += w.x*v.x + w.y*v.y + w.z*v.z + w.w*v.w;
  }
  acc += fcb[j*512 + e];
  mu[(b*19 + j)*512 + e] = fmaxf(acc, 0.f);
}

// ---- pack spade weights -> fp8 e4m3, fixed scale x2^6: wq[k5][n][c] --------
__global__ __launch_bounds__(256) void k_pack_spade(
    const float* __restrict__ g, const float* __restrict__ bt,
    uint8_t* __restrict__ wq) {
  int n = blockIdx.x;                               // 0..511
  const float* src = (n < 256) ? g + (size_t)n*12800 : bt + (size_t)(n-256)*12800;
  __shared__ float s[12800];
  for (int i = threadIdx.x; i < 12800; i += 256) s[i] = src[i];
  __syncthreads();
  int t = threadIdx.x;
  for (int k5 = 0; k5 < 25; ++k5) {
    float w0 = s[(2*t)*25 + k5] * 64.f, w1 = s[(2*t+1)*25 + k5] * 64.f;
    int pk = __builtin_amdgcn_cvt_pk_fp8_f32(w0, w1, 0, false);
    *(unsigned short*)(wq + ((size_t)k5*512 + n)*512 + 2*t) = (unsigned short)pk;
  }
}

// ---- A[b,j,k5,n] = sum_c mu[b,j,c]*wpa[k5][c][n]  (mu via scalar loads) ----
__global__ __launch_bounds__(512) void k_A_avg(const float* __restrict__ mu,
                                               const float* __restrict__ wpa,
                                               __bf16* __restrict__ A) {
  int b = blockIdx.x / 25, k5 = blockIdx.x % 25;
  int n = threadIdx.x;
  const float* wp = wpa + (size_t)k5*262144 + n;
  const float* mub = mu + b*19*512;                 // wave-uniform rows -> s_load
  float acc[19];
  #pragma unroll
  for (int j = 0; j < 19; ++j) acc[j] = 0.f;
  for (int c = 0; c < 512; ++c) {
    float w = wp[(size_t)c*512];
    #pragma unroll
    for (int j = 0; j < 19; ++j) acc[j] += mub[j*512 + c] * w;
  }
  #pragma unroll
  for (int j = 0; j < 19; ++j)
    A[((size_t)((b*19 + j)*25 + k5))*512 + n] = (__bf16)acc[j];
}

// ---- actv: debranched gather -> fp8 e4m3 (x2^8) NHWC padded ----------------
// Writes its own zero borders (rows hp<2, hp>=66 and cols wp in {0,1,66,67}).
__global__ void k_actv(const int* __restrict__ labels, const __bf16* __restrict__ wsp,
                       const float* __restrict__ ssb, uint8_t* __restrict__ actv) {
  int b = blockIdx.x / 68, hp = blockIdx.x % 68;
  int t = threadIdx.x;
  size_t rowbase = ((size_t)b*68 + hp)*68;          // padded pixel index base
  if (hp < 2 || hp >= 66) {                         // full zero row
    unsigned* dp = (unsigned*)(actv + rowbase*512);
    for (int i = t; i < 8704; i += 256) dp[i] = 0;
    return;
  }
  int h = hp - 2;
  __shared__ int lab[5*68];
  for (int i = t; i < 5*68; i += 256) {
    int dh = i / 68, xx = i % 68;
    int hh = h + dh - 2, ww = xx - 2;
    int l = 19;
    if (hh >= 0 && hh < 64 && ww >= 0 && ww < 64) {
      int l0 = labels[b*4096 + hh*64 + ww];
      if (l0 >= 0) l = l0;
    }
    lab[i] = l;
  }
  {                                                 // left/right border pixels
    unsigned* dp = (unsigned*)(actv + rowbase*512);
    dp[t] = 0; dp[66*128 + t] = 0;                  // pixels 0,1 and 66,67
  }
  __syncthreads();
  float bs0 = ssb[2*t], bs1 = ssb[2*t + 1];
  for (int w = 0; w < 64; ++w) {
    float a0 = bs0, a1 = bs1;
    #pragma unroll
    for (int tap = 0; tap < 25; ++tap) {
      int l = lab[(tap/5)*68 + w + (tap%5)];        // wave-uniform
      bf16x2 v = *(const bf16x2*)(wsp + (size_t)(l*25 + tap)*512 + 2*t);
      a0 += (float)v[0]; a1 += (float)v[1];
    }
    a0 = fmaxf(a0, 0.f) * 256.f;
    a1 = fmaxf(a1, 0.f) * 256.f;
    int pk = __builtin_amdgcn_cvt_pk_fp8_f32(a0, a1, 0, false);
    *(unsigned short*)(actv + (rowbase + 2 + w)*512 + 2*t) = (unsigned short)pk;
  }
}

// ---- implicit-GEMM conv, MXFP8 fixed-scale: M=32768, N=512, K=12800 --------
// 256x256 tile, 8 waves (wave tile 128x64), BK=128, double-buffered with
// COUNTED vmcnt (T3+T4): main loop never drains vmcnt to 0. Per chunk:
//   wait vmcnt(8)  -> own chunk-t DMA done (t+1's 8 stay in flight)
//   s_barrier      -> all waves' chunk-t data in LDS
//   compute        -> 24 ds_read_b128 + 32 MFMA (setprio around cluster)
//   s_barrier      -> all waves done READING this buffer
//   stage(t+2)     -> restage same buffer; lands during next chunk's compute
// sched_barrier(0) pins compile-time motion across the asm waits (rule #18).
__global__ __launch_bounds__(512) void k_conv(
    const uint8_t* __restrict__ actv, const uint8_t* __restrict__ wq,
    const float* __restrict__ sgb, const float* __restrict__ sbb,
    __bf16* __restrict__ gbs) {
  __shared__ __align__(16) uint8_t ldsA[2][32768];  // 256 rows x 128 B
  __shared__ __align__(16) uint8_t ldsB[2][32768];
  const int tid = threadIdx.x, wv = tid >> 6, lane = tid & 63;
  const int l15 = lane & 15, q = lane >> 4;
  const int m0 = blockIdx.x * 256, n0 = blockIdx.y * 256;
  const int b = m0 >> 12;

  int aoff[4], boff[4], ldst[4];                    // staging offsets (bytes)
  #pragma unroll
  for (int i = 0; i < 4; ++i) {
    int p = i*512 + tid;                            // 16B slot 0..2047
    int r = p >> 3, pc = p & 7;
    int cl = pc ^ (r & 7);                          // logical chunk fetched
    int pix = (m0 + r) & 4095;
    int h = pix >> 6, w = pix & 63;
    aoff[i] = ((b*68 + h)*68 + w)*512 + cl*16;
    boff[i] = (n0 + r)*512 + cl*16;
    ldst[i] = i*8192 + wv*1024;                     // wave-uniform LDS base
  }

  const int wm = (wv >> 2) * 128, wn = (wv & 3) * 64;
  f32x4 acc[8][4] = {};

  // stage K-chunk t (t = k5*4 + kc) into LDS buffer `buf` (8 vmem/wave)
  auto stage = [&](int t, int buf) {
    int k5 = t >> 2, kc = t & 3;
    int a_k = ((k5/5)*68 + (k5%5))*512 + kc*128;
    int b_k = k5*262144 + kc*128;
    uint8_t* la = &ldsA[buf][0];
    uint8_t* lb = &ldsB[buf][0];
    #pragma unroll
    for (int i = 0; i < 4; ++i) {
      gl_lds16(actv + aoff[i] + a_k, la + ldst[i]);
      gl_lds16(wq   + boff[i] + b_k, lb + ldst[i]);
    }
  };

  // compute K-chunk from LDS buffer `buf` (call with literal 0/1)
  auto compute = [&](int buf) {
    v8i bfr[4];
    #pragma unroll
    for (int ni = 0; ni < 4; ++ni) {
      int row = wn + ni*16 + l15;
      const uint8_t* base = &ldsB[buf][row*128];
      union { v8i v; uint4 u[2]; } tt;
      tt.u[0] = *(const uint4*)(base + ((2*q    ) ^ (row & 7))*16);
      tt.u[1] = *(const uint4*)(base + ((2*q + 1) ^ (row & 7))*16);
      bfr[ni] = tt.v;
    }
    __builtin_amdgcn_s_setprio(1);
    #pragma unroll
    for (int mi = 0; mi < 8; ++mi) {
      int row = wm + mi*16 + l15;
      const uint8_t* base = &ldsA[buf][row*128];
      union { v8i v; uint4 u[2]; } tt;
      tt.u[0] = *(const uint4*)(base + ((2*q    ) ^ (row & 7))*16);
      tt.u[1] = *(const uint4*)(base + ((2*q + 1) ^ (row & 7))*16);
      v8i af = tt.v;
      #pragma unroll
      for (int ni = 0; ni < 4; ++ni)
        acc[mi][ni] = __builtin_amdgcn_mfma_scale_f32_16x16x128_f8f6f4(
            af, bfr[ni], acc[mi][ni], 0, 0, 0, SCALE_A_DW, 0, SCALE_B_DW);
    }
    __builtin_amdgcn_s_setprio(0);
  };

  stage(0, 0);
  stage(1, 1);                                      // 16 vmem in flight
  #pragma unroll 1
  for (int t = 0; t < 98; t += 2) {
    asm volatile("s_waitcnt vmcnt(8)" ::: "memory");
    __builtin_amdgcn_s_barrier();
    __builtin_amdgcn_sched_barrier(0);
    compute(0);
    __builtin_amdgcn_sched_barrier(0);
    __builtin_amdgcn_s_barrier();
    __builtin_amdgcn_sched_barrier(0);
    stage(t + 2, 0);
    asm volatile("s_waitcnt vmcnt(8)" ::: "memory");
    __builtin_amdgcn_s_barrier();
    __builtin_amdgcn_sched_barrier(0);
    compute(1);
    __builtin_amdgcn_sched_barrier(0);
    __builtin_amdgcn_s_barrier();
    __builtin_amdgcn_sched_barrier(0);
    stage(t + 3, 1);
  }
  // tail: chunks 98 (buf0, chunk 99 still in flight) and 99 (buf1)
  asm volatile("s_waitcnt vmcnt(8)" ::: "memory");
  __builtin_amdgcn_s_barrier();
  __builtin_amdgcn_sched_barrier(0);
  compute(0);
  asm volatile("s_waitcnt vmcnt(0)" ::: "memory");
  __builtin_amdgcn_s_barrier();
  __builtin_amdgcn_sched_barrier(0);
  compute(1);

  // epilogue: D[row=q*4+r][col=l15]; NHWC store gbs[m][n] (+spade bias)
  #pragma unroll
  for (int ni = 0; ni < 4; ++ni) {
    int n = n0 + wn + ni*16 + l15;
    float bias = (n < 256) ? sgb[n] : sbb[n - 256];
    #pragma unroll
    for (int mi = 0; mi < 8; ++mi) {
      int m = m0 + wm + mi*16 + q*4;
      size_t base = (size_t)m*512 + n;
      #pragma unroll
      for (int r = 0; r < 4; ++r)
        gbs[base + (size_t)r*512] = (__bf16)(acc[mi][ni][r] + bias);
    }
  }
}

// ---- fused avg-gather + blend/instance-norm/NCHW-store ---------------------
// Phase 1 (thread = channel pair): 25-tap gather of gamma/beta_avg for 16
// pixels -> LDS; stage matching gbs tile -> LDS (coalesced).
// Phase 2 (thread = channel): blend avg/spade, normalize x, write out NCHW.
// Eliminates the gba global round-trip (67 MB) and the separate k_final.
__global__ __launch_bounds__(256) void k_gf(
    const int* __restrict__ labels, const __bf16* __restrict__ A,
    const float* __restrict__ cgb, const float* __restrict__ cbb,
    const __bf16* __restrict__ gbs, const float* __restrict__ x,
    const float* __restrict__ stats, const float* __restrict__ blg,
    const float* __restrict__ blb, float* __restrict__ out) {
  int wt = blockIdx.x & 3, h = (blockIdx.x >> 2) & 63, b = blockIdx.x >> 8;
  int w0 = wt * 16;
  __shared__ int rowbase[5*20];
  __shared__ __bf16 avg[16][512];
  __shared__ __bf16 spd[16][512];
  for (int i = threadIdx.x; i < 100; i += 256) {
    int dh = i / 20, xx = i % 20;
    int hh = h + dh - 2, ww = w0 + xx - 2;
    int l = (hh >= 0 && hh < 64 && ww >= 0 && ww < 64) ? labels[b*4096 + hh*64 + ww] : -1;
    rowbase[i] = (l >= 0) ? (b*19 + l)*25 : -1;
  }
  __syncthreads();
  int t = threadIdx.x;
  float bs0, bs1;
  if (2*t < 256) { bs0 = cgb[2*t]; bs1 = cgb[2*t + 1]; }
  else           { bs0 = cbb[2*t - 256]; bs1 = cbb[2*t - 255]; }
  size_t pixb = (size_t)b*4096 + h*64 + w0;
  for (int px = 0; px < 16; ++px) {
    float a0 = bs0, a1 = bs1;
    #pragma unroll
    for (int tap = 0; tap < 25; ++tap) {
      int rb = rowbase[(tap/5)*20 + px + (tap%5)];
      int row = (rb >= 0) ? rb + tap : 3800;
      bf16x2 v = *(const bf16x2*)(A + (size_t)row*512 + 2*t);
      a0 += (float)v[0]; a1 += (float)v[1];
    }
    avg[px][2*t]     = (__bf16)a0;
    avg[px][2*t + 1] = (__bf16)a1;
    *(bf16x2*)&spd[px][2*t] = *(const bf16x2*)(gbs + (pixb + px)*512 + 2*t);
  }
  __syncthreads();
  float ga = 1.f / (1.f + expf(-blg[0]));
  float ba = 1.f / (1.f + expf(-blb[0]));
  int c = threadIdx.x;                               // 0..255
  int bc = b*256 + c;
  float mean = stats[bc], rstd = stats[2048 + bc];
  size_t xb = (size_t)bc*4096 + h*64 + w0;
  #pragma unroll
  for (int pq = 0; pq < 4; ++pq) {
    float4 xv = *(const float4*)(x + xb + pq*4);
    float4 ov;
    float* xo = (float*)&xv; float* oo = (float*)&ov;
    #pragma unroll
    for (int j = 0; j < 4; ++j) {
      int px = pq*4 + j;
      float gf  = ga*(float)avg[px][c]       + (1.f - ga)*(float)spd[px][c];
      float bf_ = ba*(float)avg[px][256 + c] + (1.f - ba)*(float)spd[px][256 + c];
      oo[j] = (xo[j] - mean)*rstd*(1.f + gf) + bf_;
    }
    *(float4*)(out + xb + pq*4) = ov;
  }
}

extern "C" void kernel_launch(void* const* d_in, const int* in_sizes, int n_in,
                              void* d_out, int out_size, void* d_ws, size_t ws_size,
                              hipStream_t stream) {
  const float* x    = (const float*)d_in[0];
  const float* seg  = (const float*)d_in[1];
  const float* sc   = (const float*)d_in[2];
  const float* fcw  = (const float*)d_in[3];
  const float* fcb  = (const float*)d_in[4];
  const float* cgw  = (const float*)d_in[5];
  const float* cgb  = (const float*)d_in[6];
  const float* cbw  = (const float*)d_in[7];
  const float* cbb  = (const float*)d_in[8];
  const float* ssw  = (const float*)d_in[9];
  const float* ssb  = (const float*)d_in[10];
  const float* sgw  = (const float*)d_in[11];
  const float* sgb  = (const float*)d_in[12];
  const float* sbw  = (const float*)d_in[13];
  const float* sbb  = (const float*)d_in[14];
  const float* blg  = (const float*)d_in[15];
  const float* blb  = (const float*)d_in[16];
  float* out = (float*)d_out;

  char* ws = (char*)d_ws;
  size_t off = 0;
  auto alloc = [&](size_t bytes) {
    void* p = ws + off; off += (bytes + 255) & ~(size_t)255; return p;
  };
  float*   stats = (float*)alloc(2048ull*2*4);
  int*     labels= (int*)  alloc(32768ull*4);
  float*   mu    = (float*)alloc(77824ull*4);
  __bf16*  Aav   = (__bf16*)alloc((3800ull + 1)*512*2);  // + zero row 3800
  __bf16*  wspb  = (__bf16*)alloc(20ull*25*512*2);       // j=19 zero rows
  float*   wpa   = (float*)alloc(25ull*512*512*4);       // 26.2 MB
  uint8_t* wq    = (uint8_t*)alloc(25ull*512*512);       // 6.6 MB fp8
  uint8_t* actv  = (uint8_t*)alloc(8ull*68*68*512);      // 18.9 MB fp8 NHWC pad
  __bf16*  gbs   = (__bf16*)alloc(8ull*4096*512*2);      // 33.5 MB (NHWC)

  k_prep      <<<4201, 256, 0, stream>>>(x, stats, seg, labels, cgw, cbw, wpa, ssw, wspb, Aav);
  k_mu        <<<152, 512, 0, stream>>>(sc, fcw, fcb, mu);
  k_pack_spade<<<512, 256, 0, stream>>>(sgw, sbw, wq);
  k_A_avg     <<<200, 512, 0, stream>>>(mu, wpa, Aav);
  k_actv      <<<544, 256, 0, stream>>>(labels, wspb, ssb, actv);
  k_conv      <<<dim3(128, 2), 512, 0, stream>>>(actv, wq, sgb, sbb, gbs);
  k_gf        <<<2048, 256, 0, stream>>>(labels, Aav, cgb, cbb, gbs, x, stats, blg, blb, out);
}

// Round 3
// 639.999 us; speedup vs baseline: 1.0433x; 1.0023x over previous
//
#include <hip/hip_runtime.h>
#include <hip/hip_bf16.h>
#include <stdint.h>

typedef __attribute__((__ext_vector_type__(8))) __bf16 bf16x8;
typedef __attribute__((__ext_vector_type__(2))) __bf16 bf16x2;
typedef __attribute__((__ext_vector_type__(4))) float  f32x4;
typedef __attribute__((__ext_vector_type__(8))) int    v8i;

// Fixed MX scales (e8m0): A quantized x2^8 -> scale byte 119 (2^-8),
// B quantized x2^6 -> scale byte 121 (2^-6). Byte replicated so any
// op_sel byte selection reads the same value.
#define SCALE_A_DW 0x77777777
#define SCALE_B_DW 0x79797979

// async 16B global->LDS (dest = wave-uniform base + lane*16)
__device__ __forceinline__ void gl_lds16(const void* g, void* l) {
  __builtin_amdgcn_global_load_lds(
      (__attribute__((address_space(1))) void*)(uintptr_t)g,
      (__attribute__((address_space(3))) void*)(unsigned)(uintptr_t)l,
      16, 0, 0);
}

// ---- fused prep: stats / labels / pack_avg / pack_wsp / Aav-zero-row -------
__global__ __launch_bounds__(256) void k_prep(
    const float* __restrict__ x, float* __restrict__ stats,
    const float* __restrict__ seg, int* __restrict__ labels,
    const float* __restrict__ cgw, const float* __restrict__ cbw,
    float* __restrict__ wpa,
    const float* __restrict__ ssw, __bf16* __restrict__ wspb,
    __bf16* __restrict__ Aav) {
  __shared__ __align__(16) char smem[16*401*4];
  int blk = blockIdx.x;
  if (blk < 2048) {                       // ---- instance-norm stats
    int bc = blk;
    const float4* p = (const float4*)(x + (size_t)bc * 4096);
    float s = 0.f, ss = 0.f;
    for (int i = threadIdx.x; i < 1024; i += 256) {
      float4 v = p[i];
      s  += v.x + v.y + v.z + v.w;
      ss += v.x*v.x + v.y*v.y + v.z*v.z + v.w*v.w;
    }
    #pragma unroll
    for (int o = 32; o > 0; o >>= 1) { s += __shfl_down(s, o); ss += __shfl_down(ss, o); }
    float* sh = (float*)smem;
    int wv = threadIdx.x >> 6;
    if ((threadIdx.x & 63) == 0) { sh[wv] = s; sh[4 + wv] = ss; }
    __syncthreads();
    if (threadIdx.x == 0) {
      float S = sh[0]+sh[1]+sh[2]+sh[3], SS = sh[4]+sh[5]+sh[6]+sh[7];
      float m = S * (1.f/4096.f);
      float var = SS * (1.f/4096.f) - m*m;
      stats[bc] = m;
      stats[2048 + bc] = rsqrtf(var + 1e-5f);
    }
  } else if (blk < 2176) {                // ---- labels (last one-hot j)
    int idx = (blk - 2048)*256 + threadIdx.x;       // 0..32767
    int b = idx >> 12, pix = idx & 4095;
    const float* p = seg + (size_t)b*19*4096 + pix;
    int lab = -1;
    for (int j = 0; j < 19; ++j) if (p[(size_t)j*4096] > 0.f) lab = j;
    labels[idx] = lab;
  } else if (blk < 3200) {                // ---- pack avg weights wpa[k5][c][n]
    int bid = blk - 2176;
    float* s = (float*)smem;
    int n0 = (bid & 31) * 16, c0 = (bid >> 5) * 16;
    for (int i = threadIdx.x; i < 6400; i += 256) {
      int nn = i / 400, qq = i % 400;
      int n = n0 + nn;
      const float* src = (n < 256) ? cgw + (size_t)n*12800 : cbw + (size_t)(n-256)*12800;
      s[nn*401 + qq] = src[c0*25 + qq];
    }
    __syncthreads();
    for (int i = threadIdx.x; i < 6400; i += 256) {
      int nn = i & 15, rest = i >> 4;
      int k5 = rest % 25, cc = rest / 25;
      wpa[((size_t)k5*512 + c0 + cc)*512 + n0 + nn] = s[nn*401 + cc*25 + k5];
    }
  } else if (blk < 4200) {                // ---- pack shared weights (j=19 zero)
    int idx = (blk - 3200)*256 + threadIdx.x;       // < 256000
    int o = idx & 511, k5 = (idx >> 9) % 25, j = idx / 12800;
    wspb[idx] = (j < 19) ? (__bf16)ssw[((size_t)o*19 + j)*25 + k5] : (__bf16)0.f;
  } else {                                // ---- Aav zero row 3800
    ((unsigned*)(Aav + 3800ull*512))[threadIdx.x] = 0;   // 256 dwords = 1024 B
  }
}

// ---------------- mu[b,j,e] = relu(sum_d sc[b,j,d]*fc_w[j,e,d] + fc_b) ------
__global__ __launch_bounds__(512) void k_mu(const float* __restrict__ sc,
                                            const float* __restrict__ fcw,
                                            const float* __restrict__ fcb,
                                            float* __restrict__ mu) {
  int b = blockIdx.x / 19, j = blockIdx.x % 19;
  __shared__ float s[512];
  s[threadIdx.x] = sc[(b*19 + j)*512 + threadIdx.x];
  __syncthreads();
  int e = threadIdx.x;
  const float4* w4 = (const float4*)(fcw + ((size_t)(j*512 + e))*512);
  const float4* s4 = (const float4*)s;
  float acc = 0.f;
  for (int d = 0; d < 128; ++d) {
    float4 w = w4[d], v = s4[d];
    acc += w.x*v.x + w.y*v.y + w.z*v.z + w.w*v.w;
  }
  acc += fcb[j*512 + e];
  mu[(b*19 + j)*512 + e] = fmaxf(acc, 0.f);
}

// ---- pack spade weights -> fp8 e4m3, fixed scale x2^6: wq[k5][n][c] --------
__global__ __launch_bounds__(256) void k_pack_spade(
    const float* __restrict__ g, const float* __restrict__ bt,
    uint8_t* __restrict__ wq) {
  int n = blockIdx.x;                               // 0..511
  const float* src = (n < 256) ? g + (size_t)n*12800 : bt + (size_t)(n-256)*12800;
  __shared__ float s[12800];
  for (int i = threadIdx.x; i < 12800; i += 256) s[i] = src[i];
  __syncthreads();
  int t = threadIdx.x;
  for (int k5 = 0; k5 < 25; ++k5) {
    float w0 = s[(2*t)*25 + k5] * 64.f, w1 = s[(2*t+1)*25 + k5] * 64.f;
    int pk = __builtin_amdgcn_cvt_pk_fp8_f32(w0, w1, 0, false);
    *(unsigned short*)(wq + ((size_t)k5*512 + n)*512 + 2*t) = (unsigned short)pk;
  }
}

// ---- A[b,j,k5,n] = sum_c mu[b,j,c]*wpa[k5][c][n]  (mu via scalar loads) ----
__global__ __launch_bounds__(512) void k_A_avg(const float* __restrict__ mu,
                                               const float* __restrict__ wpa,
                                               __bf16* __restrict__ A) {
  int b = blockIdx.x / 25, k5 = blockIdx.x % 25;
  int n = threadIdx.x;
  const float* wp = wpa + (size_t)k5*262144 + n;
  const float* mub = mu + b*19*512;                 // wave-uniform rows -> s_load
  float acc[19];
  #pragma unroll
  for (int j = 0; j < 19; ++j) acc[j] = 0.f;
  for (int c = 0; c < 512; ++c) {
    float w = wp[(size_t)c*512];
    #pragma unroll
    for (int j = 0; j < 19; ++j) acc[j] += mub[j*512 + c] * w;
  }
  #pragma unroll
  for (int j = 0; j < 19; ++j)
    A[((size_t)((b*19 + j)*25 + k5))*512 + n] = (__bf16)acc[j];
}

// ---- actv: debranched gather -> fp8 e4m3 (x2^8) NHWC padded ----------------
// Writes its own zero borders (rows hp<2, hp>=66 and cols wp in {0,1,66,67}).
__global__ void k_actv(const int* __restrict__ labels, const __bf16* __restrict__ wsp,
                       const float* __restrict__ ssb, uint8_t* __restrict__ actv) {
  int b = blockIdx.x / 68, hp = blockIdx.x % 68;
  int t = threadIdx.x;
  size_t rowbase = ((size_t)b*68 + hp)*68;          // padded pixel index base
  if (hp < 2 || hp >= 66) {                         // full zero row
    unsigned* dp = (unsigned*)(actv + rowbase*512);
    for (int i = t; i < 8704; i += 256) dp[i] = 0;
    return;
  }
  int h = hp - 2;
  __shared__ int lab[5*68];
  for (int i = t; i < 5*68; i += 256) {
    int dh = i / 68, xx = i % 68;
    int hh = h + dh - 2, ww = xx - 2;
    int l = 19;
    if (hh >= 0 && hh < 64 && ww >= 0 && ww < 64) {
      int l0 = labels[b*4096 + hh*64 + ww];
      if (l0 >= 0) l = l0;
    }
    lab[i] = l;
  }
  {                                                 // left/right border pixels
    unsigned* dp = (unsigned*)(actv + rowbase*512);
    dp[t] = 0; dp[66*128 + t] = 0;                  // pixels 0,1 and 66,67
  }
  __syncthreads();
  float bs0 = ssb[2*t], bs1 = ssb[2*t + 1];
  for (int w = 0; w < 64; ++w) {
    float a0 = bs0, a1 = bs1;
    #pragma unroll
    for (int tap = 0; tap < 25; ++tap) {
      int l = lab[(tap/5)*68 + w + (tap%5)];        // wave-uniform
      bf16x2 v = *(const bf16x2*)(wsp + (size_t)(l*25 + tap)*512 + 2*t);
      a0 += (float)v[0]; a1 += (float)v[1];
    }
    a0 = fmaxf(a0, 0.f) * 256.f;
    a1 = fmaxf(a1, 0.f) * 256.f;
    int pk = __builtin_amdgcn_cvt_pk_fp8_f32(a0, a1, 0, false);
    *(unsigned short*)(actv + (rowbase + 2 + w)*512 + 2*t) = (unsigned short)pk;
  }
}

// ---- implicit-GEMM conv, MXFP8 fixed-scale: M=32768, N=512, K=12800 --------
// 256x256 tile, 8 waves (wave tile 128x64), BK=128, double-buffered with
// COUNTED vmcnt (T3+T4). R3: compute() restructured into clustered
// sub-phases -- batch ds_reads, sched_barrier, pure-MFMA cluster under
// setprio -- so the 2 waves/SIMD interleave LDS and MFMA pipes instead of
// phase-aliasing (T5's role-split prerequisite).
__global__ __launch_bounds__(512) void k_conv(
    const uint8_t* __restrict__ actv, const uint8_t* __restrict__ wq,
    const float* __restrict__ sgb, const float* __restrict__ sbb,
    __bf16* __restrict__ gbs) {
  __shared__ __align__(16) uint8_t ldsA[2][32768];  // 256 rows x 128 B
  __shared__ __align__(16) uint8_t ldsB[2][32768];
  const int tid = threadIdx.x, wv = tid >> 6, lane = tid & 63;
  const int l15 = lane & 15, q = lane >> 4;
  const int m0 = blockIdx.x * 256, n0 = blockIdx.y * 256;
  const int b = m0 >> 12;

  int aoff[4], boff[4], ldst[4];                    // staging offsets (bytes)
  #pragma unroll
  for (int i = 0; i < 4; ++i) {
    int p = i*512 + tid;                            // 16B slot 0..2047
    int r = p >> 3, pc = p & 7;
    int cl = pc ^ (r & 7);                          // logical chunk fetched
    int pix = (m0 + r) & 4095;
    int h = pix >> 6, w = pix & 63;
    aoff[i] = ((b*68 + h)*68 + w)*512 + cl*16;
    boff[i] = (n0 + r)*512 + cl*16;
    ldst[i] = i*8192 + wv*1024;                     // wave-uniform LDS base
  }

  const int wm = (wv >> 2) * 128, wn = (wv & 3) * 64;
  f32x4 acc[8][4] = {};

  // stage K-chunk t (t = k5*4 + kc) into LDS buffer `buf` (8 vmem/wave)
  auto stage = [&](int t, int buf) {
    int k5 = t >> 2, kc = t & 3;
    int a_k = ((k5/5)*68 + (k5%5))*512 + kc*128;
    int b_k = k5*262144 + kc*128;
    uint8_t* la = &ldsA[buf][0];
    uint8_t* lb = &ldsB[buf][0];
    #pragma unroll
    for (int i = 0; i < 4; ++i) {
      gl_lds16(actv + aoff[i] + a_k, la + ldst[i]);
      gl_lds16(wq   + boff[i] + b_k, lb + ldst[i]);
    }
  };

  // read one 16-row fragment (2 swizzled b128) from an LDS tile
  auto frag = [&](const uint8_t* ldst_, int row) -> v8i {
    const uint8_t* base = ldst_ + row*128;
    union { v8i v; uint4 u[2]; } tt;
    tt.u[0] = *(const uint4*)(base + ((2*q    ) ^ (row & 7))*16);
    tt.u[1] = *(const uint4*)(base + ((2*q + 1) ^ (row & 7))*16);
    return tt.v;
  };

  // compute K-chunk from LDS buffer `buf` (call with literal 0/1).
  // Two sub-phases: {batch 16 ds_reads -> 16-MFMA cluster} x2.
  auto compute = [&](int buf) {
    v8i bfr[4], afr[4];
    #pragma unroll
    for (int ni = 0; ni < 4; ++ni) bfr[ni] = frag(&ldsB[buf][0], wn + ni*16 + l15);
    #pragma unroll
    for (int mi = 0; mi < 4; ++mi) afr[mi] = frag(&ldsA[buf][0], wm + mi*16 + l15);
    __builtin_amdgcn_sched_barrier(0);
    __builtin_amdgcn_s_setprio(1);
    #pragma unroll
    for (int mi = 0; mi < 4; ++mi)
      #pragma unroll
      for (int ni = 0; ni < 4; ++ni)
        acc[mi][ni] = __builtin_amdgcn_mfma_scale_f32_16x16x128_f8f6f4(
            afr[mi], bfr[ni], acc[mi][ni], 0, 0, 0, SCALE_A_DW, 0, SCALE_B_DW);
    __builtin_amdgcn_s_setprio(0);
    __builtin_amdgcn_sched_barrier(0);
    #pragma unroll
    for (int mi = 0; mi < 4; ++mi) afr[mi] = frag(&ldsA[buf][0], wm + 64 + mi*16 + l15);
    __builtin_amdgcn_sched_barrier(0);
    __builtin_amdgcn_s_setprio(1);
    #pragma unroll
    for (int mi = 0; mi < 4; ++mi)
      #pragma unroll
      for (int ni = 0; ni < 4; ++ni)
        acc[4 + mi][ni] = __builtin_amdgcn_mfma_scale_f32_16x16x128_f8f6f4(
            afr[mi], bfr[ni], acc[4 + mi][ni], 0, 0, 0, SCALE_A_DW, 0, SCALE_B_DW);
    __builtin_amdgcn_s_setprio(0);
    __builtin_amdgcn_sched_barrier(0);
  };

  stage(0, 0);
  stage(1, 1);                                      // 16 vmem in flight
  #pragma unroll 1
  for (int t = 0; t < 98; t += 2) {
    asm volatile("s_waitcnt vmcnt(8)" ::: "memory");
    __builtin_amdgcn_s_barrier();
    __builtin_amdgcn_sched_barrier(0);
    compute(0);
    __builtin_amdgcn_s_barrier();
    __builtin_amdgcn_sched_barrier(0);
    stage(t + 2, 0);
    asm volatile("s_waitcnt vmcnt(8)" ::: "memory");
    __builtin_amdgcn_s_barrier();
    __builtin_amdgcn_sched_barrier(0);
    compute(1);
    __builtin_amdgcn_s_barrier();
    __builtin_amdgcn_sched_barrier(0);
    stage(t + 3, 1);
  }
  // tail: chunks 98 (buf0, chunk 99 still in flight) and 99 (buf1)
  asm volatile("s_waitcnt vmcnt(8)" ::: "memory");
  __builtin_amdgcn_s_barrier();
  __builtin_amdgcn_sched_barrier(0);
  compute(0);
  asm volatile("s_waitcnt vmcnt(0)" ::: "memory");
  __builtin_amdgcn_s_barrier();
  __builtin_amdgcn_sched_barrier(0);
  compute(1);

  // epilogue: D[row=q*4+r][col=l15]; NHWC store gbs[m][n] (+spade bias)
  #pragma unroll
  for (int ni = 0; ni < 4; ++ni) {
    int n = n0 + wn + ni*16 + l15;
    float bias = (n < 256) ? sgb[n] : sbb[n - 256];
    #pragma unroll
    for (int mi = 0; mi < 8; ++mi) {
      int m = m0 + wm + mi*16 + q*4;
      size_t base = (size_t)m*512 + n;
      #pragma unroll
      for (int r = 0; r < 4; ++r)
        gbs[base + (size_t)r*512] = (__bf16)(acc[mi][ni][r] + bias);
    }
  }
}

// ---- fused avg-gather + blend/instance-norm/NCHW-store ---------------------
// Phase 1 (thread = channel pair): 25-tap gather of gamma/beta_avg for 16
// pixels -> LDS; stage matching gbs tile -> LDS (coalesced).
// Phase 2 (thread = channel): blend avg/spade, normalize x, write out NCHW.
__global__ __launch_bounds__(256) void k_gf(
    const int* __restrict__ labels, const __bf16* __restrict__ A,
    const float* __restrict__ cgb, const float* __restrict__ cbb,
    const __bf16* __restrict__ gbs, const float* __restrict__ x,
    const float* __restrict__ stats, const float* __restrict__ blg,
    const float* __restrict__ blb, float* __restrict__ out) {
  int wt = blockIdx.x & 3, h = (blockIdx.x >> 2) & 63, b = blockIdx.x >> 8;
  int w0 = wt * 16;
  __shared__ int rowbase[5*20];
  __shared__ __bf16 avg[16][512];
  __shared__ __bf16 spd[16][512];
  for (int i = threadIdx.x; i < 100; i += 256) {
    int dh = i / 20, xx = i % 20;
    int hh = h + dh - 2, ww = w0 + xx - 2;
    int l = (hh >= 0 && hh < 64 && ww >= 0 && ww < 64) ? labels[b*4096 + hh*64 + ww] : -1;
    rowbase[i] = (l >= 0) ? (b*19 + l)*25 : -1;
  }
  __syncthreads();
  int t = threadIdx.x;
  float bs0, bs1;
  if (2*t < 256) { bs0 = cgb[2*t]; bs1 = cgb[2*t + 1]; }
  else           { bs0 = cbb[2*t - 256]; bs1 = cbb[2*t - 255]; }
  size_t pixb = (size_t)b*4096 + h*64 + w0;
  for (int px = 0; px < 16; ++px) {
    float a0 = bs0, a1 = bs1;
    #pragma unroll
    for (int tap = 0; tap < 25; ++tap) {
      int rb = rowbase[(tap/5)*20 + px + (tap%5)];
      int row = (rb >= 0) ? rb + tap : 3800;
      bf16x2 v = *(const bf16x2*)(A + (size_t)row*512 + 2*t);
      a0 += (float)v[0]; a1 += (float)v[1];
    }
    avg[px][2*t]     = (__bf16)a0;
    avg[px][2*t + 1] = (__bf16)a1;
    *(bf16x2*)&spd[px][2*t] = *(const bf16x2*)(gbs + (pixb + px)*512 + 2*t);
  }
  __syncthreads();
  float ga = 1.f / (1.f + expf(-blg[0]));
  float ba = 1.f / (1.f + expf(-blb[0]));
  int c = threadIdx.x;                               // 0..255
  int bc = b*256 + c;
  float mean = stats[bc], rstd = stats[2048 + bc];
  size_t xb = (size_t)bc*4096 + h*64 + w0;
  #pragma unroll
  for (int pq = 0; pq < 4; ++pq) {
    float4 xv = *(const float4*)(x + xb + pq*4);
    float4 ov;
    float* xo = (float*)&xv; float* oo = (float*)&ov;
    #pragma unroll
    for (int j = 0; j < 4; ++j) {
      int px = pq*4 + j;
      float gf  = ga*(float)avg[px][c]       + (1.f - ga)*(float)spd[px][c];
      float bf_ = ba*(float)avg[px][256 + c] + (1.f - ba)*(float)spd[px][256 + c];
      oo[j] = (xo[j] - mean)*rstd*(1.f + gf) + bf_;
    }
    *(float4*)(out + xb + pq*4) = ov;
  }
}

extern "C" void kernel_launch(void* const* d_in, const int* in_sizes, int n_in,
                              void* d_out, int out_size, void* d_ws, size_t ws_size,
                              hipStream_t stream) {
  const float* x    = (const float*)d_in[0];
  const float* seg  = (const float*)d_in[1];
  const float* sc   = (const float*)d_in[2];
  const float* fcw  = (const float*)d_in[3];
  const float* fcb  = (const float*)d_in[4];
  const float* cgw  = (const float*)d_in[5];
  const float* cgb  = (const float*)d_in[6];
  const float* cbw  = (const float*)d_in[7];
  const float* cbb  = (const float*)d_in[8];
  const float* ssw  = (const float*)d_in[9];
  const float* ssb  = (const float*)d_in[10];
  const float* sgw  = (const float*)d_in[11];
  const float* sgb  = (const float*)d_in[12];
  const float* sbw  = (const float*)d_in[13];
  const float* sbb  = (const float*)d_in[14];
  const float* blg  = (const float*)d_in[15];
  const float* blb  = (const float*)d_in[16];
  float* out = (float*)d_out;

  char* ws = (char*)d_ws;
  size_t off = 0;
  auto alloc = [&](size_t bytes) {
    void* p = ws + off; off += (bytes + 255) & ~(size_t)255; return p;
  };
  float*   stats = (float*)alloc(2048ull*2*4);
  int*     labels= (int*)  alloc(32768ull*4);
  float*   mu    = (float*)alloc(77824ull*4);
  __bf16*  Aav   = (__bf16*)alloc((3800ull + 1)*512*2);  // + zero row 3800
  __bf16*  wspb  = (__bf16*)alloc(20ull*25*512*2);       // j=19 zero rows
  float*   wpa   = (float*)alloc(25ull*512*512*4);       // 26.2 MB
  uint8_t* wq    = (uint8_t*)alloc(25ull*512*512);       // 6.6 MB fp8
  uint8_t* actv  = (uint8_t*)alloc(8ull*68*68*512);      // 18.9 MB fp8 NHWC pad
  __bf16*  gbs   = (__bf16*)alloc(8ull*4096*512*2);      // 33.5 MB (NHWC)

  k_prep      <<<4201, 256, 0, stream>>>(x, stats, seg, labels, cgw, cbw, wpa, ssw, wspb, Aav);
  k_mu        <<<152, 512, 0, stream>>>(sc, fcw, fcb, mu);
  k_pack_spade<<<512, 256, 0, stream>>>(sgw, sbw, wq);
  k_A_avg     <<<200, 512, 0, stream>>>(mu, wpa, Aav);
  k_actv      <<<544, 256, 0, stream>>>(labels, wspb, ssb, actv);
  k_conv      <<<dim3(128, 2), 512, 0, stream>>>(actv, wq, sgb, sbb, gbs);
  k_gf        <<<2048, 256, 0, stream>>>(labels, Aav, cgb, cbb, gbs, x, stats, blg, blb, out);
}